// Round 1
// 421.148 us; speedup vs baseline: 1.3194x; 1.3194x over previous
//
#include <hip/hip_runtime.h>

// Segment-mean aggregation:
//   feat_map [1, C=128, 512, 1024] f32, seg [P=524288] i32 in [0,N=400)
//   out [N, C] f32 = per-segment mean (0 for empty segments)
//
// R5 post-mortem: k3_scatter 200us at 17% HBM, VALUBusy 5% -> latency-bound
// on the per-pixel global atomicAdd rank (524K contended device-scope
// fetch-adds on 400 words, in the critical path before every row store).
// R6: fully deterministic rank = offs[s] + base[s][histblk] + lrank.
//   s0: per-512px-block LDS histogram, assigns lrank per pixel (LDS int
//       atomics only), packs pr[p] = (lrank<<9)|s, stores hist[s][b] plain.
//   s1: per-segment exclusive scan over blocks (no atomics).
//   s2: exclusive scan over segments -> offs (+ sentinel offs[N]=P).
//   s3: scatter = pure load -> transpose -> ranked row store. ZERO atomics.
//   s5: reduce over 2048 uniform row chunks (8/CU), walk segment bounds,
//       flush partials with distinct-address float atomics (~50K total).

#define NSEG_MAX 512
#define C_FAST   128
#define C2       (C_FAST / 2)   // 64 packed-bf16 uints per pixel row
#define PXW      128            // pixels per scatter block
#define LROW     67             // LDS tile row stride in uints (bank pad)
#define HB       512            // pixels per histogram block
#define NB_MAX   1024           // max histogram blocks (P <= 512K)

__device__ __forceinline__ unsigned pk_bf16(float lo, float hi)
{
    unsigned a = __builtin_bit_cast(unsigned, lo);
    unsigned b = __builtin_bit_cast(unsigned, hi);
    a += 0x7FFFu + ((a >> 16) & 1u);     // RNE
    b += 0x7FFFu + ((b >> 16) & 1u);
    return (a >> 16) | (b & 0xFFFF0000u);
}

// ---------------- new fast path (R6) ----------------

// Per-block histogram + local rank assignment. LDS atomics only.
__global__ __launch_bounds__(128)
void s0_hist(const int* __restrict__ seg, int* __restrict__ pr,
             int* __restrict__ hist)
{
    __shared__ int h[NSEG_MAX];
    const int t = threadIdx.x, b = blockIdx.x;
    for (int i = t; i < NSEG_MAX; i += 128) h[i] = 0;
    __syncthreads();
    const long p0 = (long)b * HB;
    const int4 s4 = *(const int4*)(seg + p0 + t * 4);
    const int r0 = atomicAdd(&h[s4.x], 1);
    const int r1 = atomicAdd(&h[s4.y], 1);
    const int r2 = atomicAdd(&h[s4.z], 1);
    const int r3 = atomicAdd(&h[s4.w], 1);
    int4 pk;
    pk.x = (r0 << 9) | s4.x;  pk.y = (r1 << 9) | s4.y;
    pk.z = (r2 << 9) | s4.z;  pk.w = (r3 << 9) | s4.w;
    *(int4*)(pr + p0 + t * 4) = pk;
    __syncthreads();
    for (int i = t; i < NSEG_MAX; i += 128)
        hist[i * NB_MAX + b] = h[i];     // [s][b] layout, coalesced scan read
}

// Per-segment exclusive scan over blocks (in place) + per-segment total.
__global__ __launch_bounds__(1024)
void s1_scanb(int* __restrict__ hist, int* __restrict__ cnt, int NB)
{
    __shared__ int a[NB_MAX];
    const int s = blockIdx.x, t = threadIdx.x;
    const int v = (t < NB) ? hist[s * NB_MAX + t] : 0;
    a[t] = v;
    __syncthreads();
    for (int off = 1; off < NB_MAX; off <<= 1) {
        const int x = (t >= off) ? a[t - off] : 0;
        __syncthreads();
        a[t] += x;
        __syncthreads();
    }
    if (t < NB) hist[s * NB_MAX + t] = a[t] - v;   // exclusive base[s][b]
    if (t == NB_MAX - 1) cnt[s] = a[t];
}

// Exclusive scan over segments -> offs, with sentinel offs[NSEG_MAX] = P.
__global__ __launch_bounds__(NSEG_MAX)
void s2_scans(const int* __restrict__ cnt, int* __restrict__ offs)
{
    __shared__ int a[NSEG_MAX];
    const int t = threadIdx.x;
    const int v = cnt[t];
    a[t] = v;
    __syncthreads();
    for (int off = 1; off < NSEG_MAX; off <<= 1) {
        const int x = (t >= off) ? a[t - off] : 0;
        __syncthreads();
        a[t] += x;
        __syncthreads();
    }
    offs[t] = a[t] - v;
    if (t == NSEG_MAX - 1) offs[NSEG_MAX] = a[t];
}

// Scatter: coalesced feat reads -> bf16 LDS transpose -> ranked row stores.
// Destination = offs[s] + base[s][bh] + lrank : NO atomics anywhere.
__global__ __launch_bounds__(256)
void s3_scatter(const float* __restrict__ feat, const int* __restrict__ pr,
                const int* __restrict__ hist, const int* __restrict__ offs,
                unsigned* __restrict__ fs, long P)
{
    __shared__ unsigned tile[PXW * LROW];
    __shared__ int srank[PXW];

    const int tid = threadIdx.x;
    const long p0 = (long)blockIdx.x * PXW;
    const int bh = blockIdx.x >> 2;          // 4 scatter blocks per hist block

    if (tid < PXW) {                          // issue early; overlaps phase A
        const int v = pr[p0 + tid];
        const int s = v & (NSEG_MAX - 1);
        srank[tid] = offs[s] + hist[s * NB_MAX + bh] + (v >> 9);
    }

    const int l = tid & 31, r = tid >> 5;    // 32 lanes x 8 rows
    #pragma unroll
    for (int it = 0; it < 8; ++it) {
        const int c2 = it * 8 + r;           // covers 0..63
        const float* f0 = feat + (long)(2 * c2) * P + p0 + l * 4;
        const float4 va = *(const float4*)(f0);      // channel 2*c2
        const float4 vb = *(const float4*)(f0 + P);  // channel 2*c2+1
        unsigned* tr = tile + c2;
        const int pxb = 4 * l;
        tr[(pxb + 0) * LROW] = pk_bf16(va.x, vb.x);
        tr[(pxb + 1) * LROW] = pk_bf16(va.y, vb.y);
        tr[(pxb + 2) * LROW] = pk_bf16(va.z, vb.z);
        tr[(pxb + 3) * LROW] = pk_bf16(va.w, vb.w);
    }
    __syncthreads();

    const int wave = tid >> 6, wl = tid & 63;
    for (int px = wave; px < PXW; px += 4) {
        const unsigned u = tile[px * LROW + wl];     // 2-way banks: free
        fs[(long)srank[px] * C2 + wl] = u;
    }
}

__global__ __launch_bounds__(256)
void s4_zero(float* __restrict__ p, int n)
{
    const int i = blockIdx.x * 256 + threadIdx.x;
    if (i < n) p[i] = 0.f;
}

// Uniform row-chunk reduce: block = 4 waves x 64 contiguous sorted rows.
// Lane l owns uint column l (channels 2l, 2l+1); flush at segment bounds.
__global__ __launch_bounds__(256)
void s5_reduce(const unsigned* __restrict__ fs, const int* __restrict__ offs,
               float* __restrict__ out)
{
    __shared__ int so[NSEG_MAX + 1];
    const int tid = threadIdx.x;
    for (int i = tid; i <= NSEG_MAX; i += 256) so[i] = offs[i];
    __syncthreads();

    const int l = tid & 63;
    const int r0 = blockIdx.x * 256 + (tid >> 6) * 64;

    int lo = 0, hi = NSEG_MAX;               // largest s with so[s] <= r0
    while (lo < hi) {
        const int mid = (lo + hi + 1) >> 1;
        if (so[mid] <= r0) lo = mid; else hi = mid - 1;
    }
    int s = lo;

    float a0 = 0.f, a1 = 0.f;
    const unsigned* bp = fs + (long)r0 * C2 + l;
    #pragma unroll 1
    for (int g = 0; g < 8; ++g) {
        unsigned u[8];
        #pragma unroll
        for (int k = 0; k < 8; ++k) u[k] = bp[(long)(g * 8 + k) * C2];
        #pragma unroll
        for (int k = 0; k < 8; ++k) {
            const int rr = r0 + g * 8 + k;
            if (rr >= so[s + 1]) {           // uniform across lanes
                unsafeAtomicAdd(&out[s * C_FAST + 2 * l],     a0);
                unsafeAtomicAdd(&out[s * C_FAST + 2 * l + 1], a1);
                a0 = a1 = 0.f;
                do { ++s; } while (rr >= so[s + 1]);
            }
            a0 += __builtin_bit_cast(float, u[k] << 16);
            a1 += __builtin_bit_cast(float, u[k] & 0xFFFF0000u);
        }
    }
    unsafeAtomicAdd(&out[s * C_FAST + 2 * l],     a0);
    unsafeAtomicAdd(&out[s * C_FAST + 2 * l + 1], a1);
}

__global__ __launch_bounds__(256)
void s6_final(float* __restrict__ out, const int* __restrict__ cnt, int nc)
{
    const int t = blockIdx.x * 256 + threadIdx.x;
    if (t >= nc) return;
    const int n = cnt[t >> 7];
    const float v = out[t];
    out[t] = (n > 0) ? v / (float)n : 0.f;
}

// ---------------- old fast path (R5, kept if ws barely fits) ----------------

__global__ __launch_bounds__(512)
void k0_zero(int* __restrict__ cnt, int n)
{
    const int t = threadIdx.x;
    if (t < n) cnt[t] = 0;
}

__global__ __launch_bounds__(256)
void k1_hist(const int* __restrict__ seg, int* __restrict__ cnt, int N)
{
    __shared__ int h[NSEG_MAX];
    const int t = threadIdx.x;
    for (int i = t; i < N; i += 256) h[i] = 0;
    __syncthreads();
    const long base = (long)blockIdx.x * 1024 + t * 4;
    const int4 s4 = *(const int4*)(seg + base);
    atomicAdd(&h[s4.x], 1); atomicAdd(&h[s4.y], 1);
    atomicAdd(&h[s4.z], 1); atomicAdd(&h[s4.w], 1);
    __syncthreads();
    for (int i = t; i < N; i += 256)
        if (h[i]) atomicAdd(&cnt[i], h[i]);
}

__global__ __launch_bounds__(NSEG_MAX)
void k2_scan(const int* __restrict__ cnt, int* __restrict__ offs,
             int* __restrict__ cursor, int N)
{
    __shared__ int a[NSEG_MAX];
    const int t = threadIdx.x;
    const int v = (t < N) ? cnt[t] : 0;
    a[t] = v;
    __syncthreads();
    for (int off = 1; off < NSEG_MAX; off <<= 1) {
        const int x = (t >= off) ? a[t - off] : 0;
        __syncthreads();
        a[t] += x;
        __syncthreads();
    }
    if (t < N) { const int e = a[t] - v; offs[t] = e; cursor[t] = e; }
}

__global__ __launch_bounds__(256)
void k3_scatter(const float* __restrict__ feat, const int* __restrict__ seg,
                int* __restrict__ cursor, unsigned* __restrict__ fs, long P)
{
    __shared__ unsigned tile[PXW * LROW];
    __shared__ int srank[PXW];
    const int tid = threadIdx.x;
    const long p0 = (long)blockIdx.x * PXW;
    const int l = tid & 31, r = tid >> 5;
    #pragma unroll
    for (int it = 0; it < 8; ++it) {
        const int c2 = it * 8 + r;
        const float* f0 = feat + (long)(2 * c2) * P + p0 + l * 4;
        const float4 va = *(const float4*)(f0);
        const float4 vb = *(const float4*)(f0 + P);
        unsigned* tr = tile + c2;
        const int pxb = 4 * l;
        tr[(pxb + 0) * LROW] = pk_bf16(va.x, vb.x);
        tr[(pxb + 1) * LROW] = pk_bf16(va.y, vb.y);
        tr[(pxb + 2) * LROW] = pk_bf16(va.z, vb.z);
        tr[(pxb + 3) * LROW] = pk_bf16(va.w, vb.w);
    }
    if (tid < PXW) {
        const int s = seg[p0 + tid];
        srank[tid] = atomicAdd(&cursor[s], 1);
    }
    __syncthreads();
    const int wave = tid >> 6, wl = tid & 63;
    for (int px = wave; px < PXW; px += 4) {
        const unsigned u = tile[px * LROW + wl];
        fs[(long)srank[px] * C2 + wl] = u;
    }
}

__global__ __launch_bounds__(512)
void k4_reduce(const unsigned* __restrict__ fs, const int* __restrict__ offs,
               const int* __restrict__ cnt, float* __restrict__ out)
{
    __shared__ float red[8][C_FAST];
    const int s = blockIdx.x;
    const int tid = threadIdx.x, l = tid & 63, j = tid >> 6;
    const int start = offs[s], n = cnt[s];
    float a0 = 0.f, a1 = 0.f;
    const unsigned* base = fs + (long)start * C2 + l;
    for (int i = j; i < n; i += 8) {
        const unsigned u = base[(long)i * C2];
        a0 += __builtin_bit_cast(float, u << 16);
        a1 += __builtin_bit_cast(float, u & 0xFFFF0000u);
    }
    red[j][2 * l]     = a0;
    red[j][2 * l + 1] = a1;
    __syncthreads();
    if (tid < C_FAST) {
        float sum = 0.f;
        #pragma unroll
        for (int q = 0; q < 8; ++q) sum += red[q][tid];
        out[(long)s * C_FAST + tid] = (n > 0) ? sum / (float)n : 0.f;
    }
}

// ---------------- fallback path (R4, known-correct) ----------------

#define FB_THREADS 256
#define FB_CPB 2

__global__ __launch_bounds__(256)
void fb_zero(float* __restrict__ p, int n)
{
    const int i = blockIdx.x * 256 + threadIdx.x;
    if (i < n) p[i] = 0.f;
}

__global__ __launch_bounds__(FB_THREADS, 4)
void fb_partial(const float* __restrict__ feat, const int* __restrict__ seg,
                float* __restrict__ acc, float* __restrict__ cnt,
                long P, int N, int kIters)
{
    __shared__ float s_sum[FB_CPB][NSEG_MAX];
    __shared__ int   s_cnt[NSEG_MAX];
    const int tid = threadIdx.x;
    const int g = blockIdx.x, w = blockIdx.y;
    const int c0 = g * FB_CPB;
    const bool doCnt = (g == 0);
    for (int i = tid; i < FB_CPB * NSEG_MAX; i += FB_THREADS) (&s_sum[0][0])[i] = 0.f;
    for (int i = tid; i < NSEG_MAX; i += FB_THREADS) s_cnt[i] = 0;
    __syncthreads();
    const long pbase = (long)w * kIters * (FB_THREADS * 4);
    const int*   sp  = seg + pbase + (long)tid * 4;
    const float* fp0 = feat + (long)c0 * P + pbase + (long)tid * 4;
    const float* fp1 = fp0 + P;
    for (int k = 0; k < kIters; ++k) {
        const long off = (long)k * (FB_THREADS * 4);
        const int4 s4 = *(const int4*)(sp + off);
        const float4 a = *(const float4*)(fp0 + off);
        const float4 b = *(const float4*)(fp1 + off);
        unsafeAtomicAdd(&s_sum[0][s4.x], a.x);
        unsafeAtomicAdd(&s_sum[0][s4.y], a.y);
        unsafeAtomicAdd(&s_sum[0][s4.z], a.z);
        unsafeAtomicAdd(&s_sum[0][s4.w], a.w);
        unsafeAtomicAdd(&s_sum[1][s4.x], b.x);
        unsafeAtomicAdd(&s_sum[1][s4.y], b.y);
        unsafeAtomicAdd(&s_sum[1][s4.z], b.z);
        unsafeAtomicAdd(&s_sum[1][s4.w], b.w);
        if (doCnt) {
            atomicAdd(&s_cnt[s4.x], 1); atomicAdd(&s_cnt[s4.y], 1);
            atomicAdd(&s_cnt[s4.z], 1); atomicAdd(&s_cnt[s4.w], 1);
        }
    }
    __syncthreads();
    for (int i = tid; i < FB_CPB * N; i += FB_THREADS) {
        const int dc = i / N, s = i - dc * N;
        unsafeAtomicAdd(&acc[(long)(c0 + dc) * N + s], s_sum[dc][s]);
    }
    if (doCnt)
        for (int s = tid; s < N; s += FB_THREADS)
            unsafeAtomicAdd(&cnt[s], (float)s_cnt[s]);
}

__global__ __launch_bounds__(256)
void fb_finalize(const float* __restrict__ acc, const float* __restrict__ cnt,
                 float* __restrict__ out, int N, int C)
{
    const int t = blockIdx.x * 256 + threadIdx.x;
    if (t >= N * C) return;
    const int s = t / C, c = t - s * C;
    const float ct = cnt[s];
    out[t] = (ct > 0.f) ? acc[(long)c * N + s] / ct : 0.f;
}

// ---------------- launch ----------------

extern "C" void kernel_launch(void* const* d_in, const int* in_sizes, int n_in,
                              void* d_out, int out_size, void* d_ws, size_t ws_size,
                              hipStream_t stream)
{
    const float* feat = (const float*)d_in[0];
    const int*   seg  = (const int*)d_in[1];
    float*       out  = (float*)d_out;

    const long P = in_sizes[1];             // 524288
    const int  C = (int)(in_sizes[0] / P);  // 128
    const int  N = out_size / C;            // 400

    const int NB = (int)(P / HB);
    const size_t need_new = (size_t)P * C2 * 4 + (size_t)P * 4 +
                            (size_t)NSEG_MAX * NB_MAX * 4 +
                            (size_t)(2 * NSEG_MAX + 1) * 4;
    const size_t need_old = (size_t)P * C2 * 4 + 3u * NSEG_MAX * 4;

    const bool shapeOK = (C == C_FAST) && (N <= NSEG_MAX);
    const bool fastNew = shapeOK && (P % HB == 0) && (NB <= NB_MAX) &&
                         (P % 256 == 0) && ws_size >= need_new;
    const bool fastOld = shapeOK && (P % PXW == 0) && (P % 1024 == 0) &&
                         ws_size >= need_old;

    if (fastNew) {
        unsigned* fs = (unsigned*)d_ws;                  // [P][C2] bf16-pairs
        int* pr   = (int*)(fs + (size_t)P * C2);         // [P] (lrank<<9)|s
        int* hist = pr + P;                              // [NSEG_MAX][NB_MAX]
        int* cnt  = hist + (size_t)NSEG_MAX * NB_MAX;    // [NSEG_MAX]
        int* offs = cnt + NSEG_MAX;                      // [NSEG_MAX+1]
        const int nc = N * C_FAST;

        s0_hist  <<<NB, 128, 0, stream>>>(seg, pr, hist);
        s1_scanb <<<NSEG_MAX, 1024, 0, stream>>>(hist, cnt, NB);
        s2_scans <<<1, NSEG_MAX, 0, stream>>>(cnt, offs);
        s4_zero  <<<(nc + 255) / 256, 256, 0, stream>>>(out, nc);
        s3_scatter<<<(int)(P / PXW), 256, 0, stream>>>(feat, pr, hist, offs, fs, P);
        s5_reduce<<<(int)(P / 256), 256, 0, stream>>>(fs, offs, out);
        s6_final <<<(nc + 255) / 256, 256, 0, stream>>>(out, cnt, nc);
    } else if (fastOld) {
        unsigned* fs  = (unsigned*)d_ws;
        int* cnt    = (int*)(fs + (size_t)P * C2);
        int* offs   = cnt + NSEG_MAX;
        int* cursor = offs + NSEG_MAX;

        k0_zero  <<<1, 512, 0, stream>>>(cnt, N);
        k1_hist  <<<(int)(P / 1024), 256, 0, stream>>>(seg, cnt, N);
        k2_scan  <<<1, NSEG_MAX, 0, stream>>>(cnt, offs, cursor, N);
        k3_scatter<<<(int)(P / PXW), 256, 0, stream>>>(feat, seg, cursor, fs, P);
        k4_reduce<<<N, 512, 0, stream>>>(fs, offs, cnt, out);
    } else {
        int W = 32;
        while (W > 1 && (P % ((long)W * FB_THREADS * 4)) != 0) W >>= 1;
        const int kIters = (int)(P / ((long)W * FB_THREADS * 4));
        float* acc = (float*)d_ws;
        float* cnt = acc + (size_t)C * N;
        const int nz = C * N + N;
        fb_zero<<<(nz + 255) / 256, 256, 0, stream>>>(acc, nz);
        fb_partial<<<dim3(C / FB_CPB, W), dim3(FB_THREADS), 0, stream>>>(
            feat, seg, acc, cnt, P, N, kIters);
        fb_finalize<<<(N * C + 255) / 256, 256, 0, stream>>>(acc, cnt, out, N, C);
    }
}